// Round 9
// baseline (70.703 us; speedup 1.0000x reference)
//
#include <hip/hip_runtime.h>

// Problem constants (fixed by setup_inputs)
#define T_DIM 32
#define B_DIM 64
#define D_DIM 256
#define P_DIM 1024
#define NK    17
#define DT    0.1875f    // 3/16
#define DT_REV 0.029841551329651566f   // DT / (2*pi) -- v_sin/v_cos take revolutions

#define KC    128        // K-chunk for the MFMA tiles
#define LROW  136        // padded LDS row (128 + 8 bf16): 272 B, 16B-aligned
#define PROW  264        // prep kernel's A-tile row (256 + 8 bf16)

typedef __bf16 bf16x8 __attribute__((ext_vector_type(8)));
typedef float  f32x16 __attribute__((ext_vector_type(16)));

static __device__ __forceinline__ unsigned short f2bf(float f) {
  unsigned u = __float_as_uint(f);
  u += 0x7fffu + ((u >> 16) & 1u);     // round-to-nearest-even
  return (unsigned short)(u >> 16);
}

// ---------------------------------------------------------------------------
// K1 prep: blocks 0..15  -> ATbf[p][d] = bf16(A[d][p] / clamp(norm_p)) (transposed)
//          blocks 16..79 -> projbf = bf16(proj) (elementwise, 2048 float4/block)
// ---------------------------------------------------------------------------
__global__ __launch_bounds__(256) void prep_kernel(const float* __restrict__ proj,
                                                   const float* __restrict__ A,
                                                   unsigned short* __restrict__ projbf,
                                                   unsigned short* __restrict__ ATbf) {
  const int tid = threadIdx.x;
  if (blockIdx.x < 16) {
    __shared__ unsigned short tile[64 * PROW];   // [p][d], padded
    __shared__ float red[4][64];
    __shared__ float invn[64];
    const int pl = tid & 63;
    const int dq = tid >> 6;                     // 0..3
    const int p0 = blockIdx.x * 64;
    const float* Ac = A + p0 + pl;
    float s = 0.f;
#pragma unroll 8
    for (int i = 0; i < 64; ++i) {
      float v = Ac[(size_t)(dq * 64 + i) * P_DIM];   // coalesced over pl
      s = fmaf(v, v, s);
    }
    red[dq][pl] = s;
    __syncthreads();
    if (tid < 64) {
      float tot = red[0][pl] + red[1][pl] + red[2][pl] + red[3][pl];
      invn[pl] = rsqrtf(fmaxf(tot, 1e-24f));     // 1/clamp_min(norm,1e-12)
    }
    __syncthreads();
    const float inv = invn[pl];
#pragma unroll 8
    for (int i = 0; i < 64; ++i) {
      int d = dq * 64 + i;
      float v = Ac[(size_t)d * P_DIM] * inv;     // L2-warm re-read
      tile[pl * PROW + d] = f2bf(v);
    }
    __syncthreads();
    // cooperative coalesced store: 64 rows x 256 bf16 (strip the pad)
#pragma unroll
    for (int r = 0; r < 8; ++r) {
      int idx = tid + r * 256;                   // 0..2047 uint4 units
      int row = idx >> 5, c = idx & 31;
      uint4 v = *(const uint4*)&tile[row * PROW + c * 8];
      *(uint4*)(ATbf + ((size_t)(p0 + row) * D_DIM + c * 8)) = v;
    }
  } else {
    // proj cast: 64 blocks x 2048 float4 each (proj = 131072 float4 total)
    const int pb = blockIdx.x - 16;
    const float4* src = (const float4*)proj + (size_t)pb * 2048;
    unsigned short* dst = projbf + (size_t)pb * 8192;
#pragma unroll
    for (int r = 0; r < 8; ++r) {
      int i = tid + r * 256;                     // 0..2047
      float4 v = src[i];
      ushort4 o;
      o.x = f2bf(v.x); o.y = f2bf(v.y); o.z = f2bf(v.z); o.w = f2bf(v.w);
      *(ushort4*)(dst + (size_t)i * 4) = o;
    }
  }
}

// ---------------------------------------------------------------------------
// K2 main: 1D grid of 512, 256 thr (4 waves).
// XCD swizzle: block id = pt*32 + t, so XCD = id % 8 = t % 8 -> the 16
// p-tile blocks sharing one proj t-tile all land on ONE XCD's L2 (one
// fetch, not eight). A-bf16 (0.5 MB) is L2-resident everywhere.
// X = projbf @ ATbf^T via 32x32x16 bf16 MFMA, K chunked 2x128 (34816 B LDS).
// Wave wv owns tile (mt=wv>>1 of b, nt=wv&1 of p). HW trig Chebyshev,
// cos/sin sums over B, weighted error -> partials[block].
// ---------------------------------------------------------------------------
__global__ __launch_bounds__(256) void sig_main_kernel(const unsigned short* __restrict__ projbf,
                                                       const unsigned short* __restrict__ ATbf,
                                                       float* __restrict__ partials) {
  __shared__ unsigned short sm[2 * 64 * LROW];   // 34816 B
  float* smf = (float*)sm;                       // reduction-plane alias
  const int tid  = threadIdx.x;
  const int lane = tid & 63;
  const int wv   = tid >> 6;                     // 0..3
  const int bid  = blockIdx.x;
  const int pt   = bid >> 5;                     // 0..15
  const int t    = bid & 31;                     // 0..31 -> XCD = t % 8
  const int p0   = pt * 64;

  unsigned short* sp = sm;                       // proj chunk [b][k] (padded)
  unsigned short* sa = sm + 64 * LROW;           // A^T chunk  [p][k] (padded)

  const unsigned short* gp = projbf + (size_t)t * B_DIM * D_DIM;
  const unsigned short* ga = ATbf + (size_t)p0 * D_DIM;

  const int mt = wv >> 1, nt = wv & 1;
  const int mrow = mt * 32 + (lane & 31);        // b row
  const int nrow = nt * 32 + (lane & 31);        // p row
  const int koff = (lane >> 5) * 8;

  f32x16 acc = {0.f, 0.f, 0.f, 0.f, 0.f, 0.f, 0.f, 0.f,
                0.f, 0.f, 0.f, 0.f, 0.f, 0.f, 0.f, 0.f};

  for (int kc = 0; kc < D_DIM; kc += KC) {
    // ---- stage chunk: 64 rows x 128 bf16 per tile (1024 uint4 each) ----
#pragma unroll
    for (int r = 0; r < 4; ++r) {
      int idx = tid + r * 256;                   // 0..1023
      int row = idx >> 4, c = idx & 15;
      uint4 v = *(const uint4*)(gp + (size_t)row * D_DIM + kc + c * 8);
      *(uint4*)&sp[row * LROW + c * 8] = v;
      uint4 w = *(const uint4*)(ga + (size_t)row * D_DIM + kc + c * 8);
      *(uint4*)&sa[row * LROW + c * 8] = w;
    }
    __syncthreads();

    // ---- MFMA over this chunk: 8 k-steps ----
#pragma unroll
    for (int ks = 0; ks < 8; ++ks) {
      int k = ks * 16 + koff;
      bf16x8 af = *(const bf16x8*)&sp[mrow * LROW + k];
      bf16x8 bf = *(const bf16x8*)&sa[nrow * LROW + k];
      acc = __builtin_amdgcn_mfma_f32_32x32x16_bf16(af, bf, acc, 0, 0, 0);
    }
    __syncthreads();                             // reads done before restage/reuse
  }
  // acc reg r holds x[b = mt*32+(r&3)+8*(r>>2)+4*(lane>>5)][p = nt*32+(lane&31)]

  // ---- Chebyshev trig via HW v_sin/v_cos (revolutions): k = 1..16 sums ----
  float cs[NK - 1], ss[NK - 1];
#pragma unroll
  for (int k = 0; k < NK - 1; ++k) { cs[k] = 0.f; ss[k] = 0.f; }
#pragma unroll
  for (int r = 0; r < 16; ++r) {
    float th = acc[r] * DT_REV;                  // revolutions, |th| << 1
    float c1 = __builtin_amdgcn_cosf(th);        // cos(2*pi*th) = cos(x*DT)
    float s1 = __builtin_amdgcn_sinf(th);
    float twoc = 2.f * c1;
    float ckm1 = 1.f, skm1 = 0.f;
    float ck = c1, sk = s1;
    cs[0] += c1;
    ss[0] += s1;
#pragma unroll
    for (int k = 2; k < NK; ++k) {
      float cn = fmaf(twoc, ck, -ckm1);
      float sn = fmaf(twoc, sk, -skm1);
      cs[k - 1] += cn;
      ss[k - 1] += sn;
      ckm1 = ck; skm1 = sk; ck = cn; sk = sn;
    }
  }

  // ---- combine the two b-halves (lane L and L^32 share the same p col) ----
#pragma unroll
  for (int k = 0; k < NK - 1; ++k) {
    cs[k] += __shfl_xor(cs[k], 32, 64);
    ss[k] += __shfl_xor(ss[k], 32, 64);
  }

  // ---- planes: cos[16][2 mt][64 p] @0, sin @2048 (LDS reuse) ----
  if (lane < 32) {
    int p = nt * 32 + (lane & 31);
#pragma unroll
    for (int k = 0; k < NK - 1; ++k) {
      smf[k * 128 + mt * 64 + p]        = cs[k];
      smf[2048 + k * 128 + mt * 64 + p] = ss[k];
    }
  }
  __syncthreads();

  // ---- per-(k,p) error + weight dot ----
  float part = 0.f;
#pragma unroll
  for (int r = 0; r < 4; ++r) {
    int e  = tid + r * 256;                      // 0..1023
    int k1 = e >> 6;
    int pl = e & 63;
    float C = smf[k1 * 128 + pl] + smf[k1 * 128 + 64 + pl];
    float S = smf[2048 + k1 * 128 + pl] + smf[2048 + k1 * 128 + 64 + pl];
    float cm  = C * (1.f / 64.f);
    float sm_ = S * (1.f / 64.f);
    float tk  = (float)(k1 + 1) * DT;
    float phi = __expf(-0.5f * tk * tk);
    float wk  = ((k1 == NK - 2) ? DT : 2.f * DT) * phi;   // k=16 endpoint
    float dc  = cm - phi;
    part = fmaf(wk, fmaf(dc, dc, sm_ * sm_), part);
  }
  part *= (1.f / 512.f);                         // * B / (T*P)

  // ---- block reduce -> one partial per block ----
#pragma unroll
  for (int off = 32; off > 0; off >>= 1)
    part += __shfl_down(part, off, 64);
  __syncthreads();                               // done reading planes
  if (lane == 0) smf[4096 + wv] = part;
  __syncthreads();
  if (tid == 0)
    partials[bid] = smf[4096] + smf[4097] + smf[4098] + smf[4099];
}

// ---------------------------------------------------------------------------
// Finalize: sum 512 block partials -> scalar
// ---------------------------------------------------------------------------
__global__ __launch_bounds__(256) void sig_finalize_kernel(const float* __restrict__ partials,
                                                           float* __restrict__ out) {
  __shared__ float red[4];
  const int tid  = threadIdx.x;
  const int lane = tid & 63;
  const int wave = tid >> 6;
  float v = partials[tid] + partials[tid + 256];
#pragma unroll
  for (int off = 32; off > 0; off >>= 1)
    v += __shfl_down(v, off, 64);
  if (lane == 0) red[wave] = v;
  __syncthreads();
  if (tid == 0) out[0] = red[0] + red[1] + red[2] + red[3];
}

// ---------------------------------------------------------------------------
extern "C" void kernel_launch(void* const* d_in, const int* in_sizes, int n_in,
                              void* d_out, int out_size, void* d_ws, size_t ws_size,
                              hipStream_t stream) {
  const float* proj = (const float*)d_in[0];     // (32,64,256) fp32
  const float* A    = (const float*)d_in[1];     // (256,1024) fp32
  float* out        = (float*)d_out;             // 1 fp32 scalar

  unsigned short* projbf = (unsigned short*)d_ws;                              // 512K bf16 = 1 MB
  unsigned short* ATbf   = (unsigned short*)((char*)d_ws + 1536u * 1024);      // 256K bf16
  float* partials        = (float*)((char*)d_ws + 2560u * 1024);               // 512 floats

  prep_kernel<<<dim3(80), dim3(256), 0, stream>>>(proj, A, projbf, ATbf);
  sig_main_kernel<<<dim3(512), dim3(256), 0, stream>>>(projbf, ATbf, partials);
  sig_finalize_kernel<<<dim3(1), dim3(256), 0, stream>>>(partials, out);
}